// Round 1
// baseline (524.088 us; speedup 1.0000x reference)
//
#include <hip/hip_runtime.h>
#include <math.h>

#define N 4096
#define S0 256
#define S1 128
#define S2 64

// ---------------- small chained GEMMs ----------------

// T1 = U0 @ U1 : (N,S0)@(S0,S1) -> (N,S1). 8 rows per block, 128 threads.
__global__ __launch_bounds__(128) void k_t1(const float* __restrict__ U0,
                                            const float* __restrict__ U1,
                                            float* __restrict__ T1) {
    __shared__ float u0s[8][S0];
    int i0 = blockIdx.x * 8;
    int tid = threadIdx.x;
    for (int t = tid; t < 8 * S0; t += 128)
        u0s[t / S0][t % S0] = U0[(i0 + t / S0) * S0 + (t % S0)];
    __syncthreads();
    int j = tid;
    float acc[8] = {0, 0, 0, 0, 0, 0, 0, 0};
    for (int k = 0; k < S0; ++k) {
        float u1 = U1[k * S1 + j];
#pragma unroll
        for (int r = 0; r < 8; ++r) acc[r] += u0s[r][k] * u1;
    }
    for (int r = 0; r < 8; ++r) T1[(i0 + r) * S1 + j] = acc[r];
}

// W = T1 @ U2 : (N,S1)@(S1,S2) -> (N,S2). 8 rows per block, 64 threads.
__global__ __launch_bounds__(64) void k_w(const float* __restrict__ T1,
                                          const float* __restrict__ U2,
                                          float* __restrict__ W) {
    __shared__ float ts[8][S1];
    int i0 = blockIdx.x * 8;
    int tid = threadIdx.x;
    for (int t = tid; t < 8 * S1; t += 64)
        ts[t / S1][t % S1] = T1[(i0 + t / S1) * S1 + (t % S1)];
    __syncthreads();
    int j = tid;
    float acc[8] = {0, 0, 0, 0, 0, 0, 0, 0};
    for (int k = 0; k < S1; ++k) {
        float u2 = U2[k * S2 + j];
#pragma unroll
        for (int r = 0; r < 8; ++r) acc[r] += ts[r][k] * u2;
    }
    for (int r = 0; r < 8; ++r) W[(i0 + r) * S2 + j] = acc[r];
}

// H1 = elu(V2^T @ fc1_w^T + fc1_b) : (N,S1). 8 rows per block, 128 threads.
__global__ __launch_bounds__(128) void k_h1(const float* __restrict__ V2,
                                            const float* __restrict__ fc1_w,
                                            const float* __restrict__ fc1_b,
                                            float* __restrict__ H1) {
    __shared__ float vs[8][S2];
    int i0 = blockIdx.x * 8;
    int tid = threadIdx.x;
    for (int t = tid; t < 8 * S2; t += 128) {
        int r = t % 8, k = t / 8;
        vs[r][k] = V2[k * N + i0 + r];
    }
    __syncthreads();
    int j = tid;
    float b = fc1_b[j];
    float acc[8];
#pragma unroll
    for (int r = 0; r < 8; ++r) acc[r] = b;
    for (int k = 0; k < S2; ++k) {
        float w = fc1_w[j * S2 + k];
#pragma unroll
        for (int r = 0; r < 8; ++r) acc[r] += vs[r][k] * w;
    }
    for (int r = 0; r < 8; ++r) {
        float x = acc[r];
        H1[(i0 + r) * S1 + j] = x > 0.f ? x : (expf(x) - 1.f);
    }
}

// H = H1 @ fc2_w^T + fc2_b, then L2-normalize rows -> hn (N,S0).
// 8 rows per block, 256 threads.
__global__ __launch_bounds__(256) void k_hn(const float* __restrict__ H1,
                                            const float* __restrict__ fc2_w,
                                            const float* __restrict__ fc2_b,
                                            float* __restrict__ hn) {
    __shared__ float hs[8][S1];
    __shared__ float red[4][8];
    __shared__ float norms[8];
    int i0 = blockIdx.x * 8;
    int tid = threadIdx.x;
    for (int t = tid; t < 8 * S1; t += 256)
        hs[t / S1][t % S1] = H1[(i0 + t / S1) * S1 + (t % S1)];
    __syncthreads();
    int j = tid;
    float b = fc2_b[j];
    float acc[8];
#pragma unroll
    for (int r = 0; r < 8; ++r) acc[r] = b;
    for (int k = 0; k < S1; ++k) {
        float w = fc2_w[j * S1 + k];
#pragma unroll
        for (int r = 0; r < 8; ++r) acc[r] += hs[r][k] * w;
    }
    int lane = tid & 63, wave = tid >> 6;
#pragma unroll
    for (int r = 0; r < 8; ++r) {
        float v = acc[r] * acc[r];
        for (int off = 32; off; off >>= 1) v += __shfl_down(v, off, 64);
        if (lane == 0) red[wave][r] = v;
    }
    __syncthreads();
    if (tid < 8) {
        float s = red[0][tid] + red[1][tid] + red[2][tid] + red[3][tid];
        norms[tid] = fmaxf(sqrtf(s), 1e-12f);
    }
    __syncthreads();
    for (int r = 0; r < 8; ++r) hn[(i0 + r) * S0 + j] = acc[r] / norms[r];
}

// ---------------- loss1: sum((A - W@V2)^2), 64x64 tiles, K=64 ----------------

__global__ __launch_bounds__(256) void k_loss1(const float* __restrict__ W,
                                               const float* __restrict__ V2,
                                               const float* __restrict__ A,
                                               double* __restrict__ acc) {
    __shared__ float Ws[64 * 68];
    __shared__ float Vs[64 * 68];
    __shared__ double redd[4];
    int i0 = blockIdx.y * 64, j0 = blockIdx.x * 64;
    int tid = threadIdx.x;
    int tx = tid & 15, ty = tid >> 4;
    for (int idx = tid; idx < 1024; idx += 256) {
        int r = idx >> 4, c4 = idx & 15;
        *(float4*)&Ws[r * 68 + c4 * 4] = *(const float4*)&W[(i0 + r) * S2 + c4 * 4];
        *(float4*)&Vs[r * 68 + c4 * 4] = *(const float4*)&V2[r * N + j0 + c4 * 4];
    }
    __syncthreads();
    float d[4][4] = {};
    for (int k = 0; k < 64; k += 4) {
        float4 av[4], bv[4];
#pragma unroll
        for (int a = 0; a < 4; ++a) av[a] = *(float4*)&Ws[(ty * 4 + a) * 68 + k];
#pragma unroll
        for (int kk = 0; kk < 4; ++kk) bv[kk] = *(float4*)&Vs[(k + kk) * 68 + tx * 4];
#pragma unroll
        for (int a = 0; a < 4; ++a) {
            d[a][0] += av[a].x * bv[0].x + av[a].y * bv[1].x + av[a].z * bv[2].x + av[a].w * bv[3].x;
            d[a][1] += av[a].x * bv[0].y + av[a].y * bv[1].y + av[a].z * bv[2].y + av[a].w * bv[3].y;
            d[a][2] += av[a].x * bv[0].z + av[a].y * bv[1].z + av[a].z * bv[2].z + av[a].w * bv[3].z;
            d[a][3] += av[a].x * bv[0].w + av[a].y * bv[1].w + av[a].z * bv[2].w + av[a].w * bv[3].w;
        }
    }
    float local = 0.f;
#pragma unroll
    for (int a = 0; a < 4; ++a) {
        float4 av = *(const float4*)&A[(i0 + ty * 4 + a) * N + j0 + tx * 4];
        float e0 = av.x - d[a][0], e1 = av.y - d[a][1];
        float e2 = av.z - d[a][2], e3 = av.w - d[a][3];
        local += e0 * e0 + e1 * e1 + e2 * e2 + e3 * e3;
    }
    int lane = tid & 63, wave = tid >> 6;
    double dl = (double)local;
    for (int off = 32; off; off >>= 1) dl += __shfl_down(dl, off, 64);
    if (lane == 0) redd[wave] = dl;
    __syncthreads();
    if (tid == 0) atomicAdd(acc, redd[0] + redd[1] + redd[2] + redd[3]);
}

// ------- fused refl_sim pass: rowsum + sim-mask pos sum, 64x64 tiles -------

__global__ __launch_bounds__(256) void k_sim(const float* __restrict__ hn,
                                             const float* __restrict__ sim,
                                             float* __restrict__ rowsum,
                                             float* __restrict__ pos4) {
    __shared__ float As[64 * 68];
    __shared__ float Bs[64 * 68];
    __shared__ float redS[64], redP[64];
    int i0 = blockIdx.y * 64, j0 = blockIdx.x * 64;
    int tid = threadIdx.x, tx = tid & 15, ty = tid >> 4;
    float d[4][4] = {};
    for (int k0 = 0; k0 < S0; k0 += 64) {
        __syncthreads();
        for (int idx = tid; idx < 1024; idx += 256) {
            int r = idx >> 4, c4 = idx & 15;
            *(float4*)&As[r * 68 + c4 * 4] = *(const float4*)&hn[(i0 + r) * S0 + k0 + c4 * 4];
            *(float4*)&Bs[r * 68 + c4 * 4] = *(const float4*)&hn[(j0 + r) * S0 + k0 + c4 * 4];
        }
        __syncthreads();
        for (int k = 0; k < 64; k += 4) {
            float4 av[4], bv[4];
#pragma unroll
            for (int a = 0; a < 4; ++a) av[a] = *(float4*)&As[(ty * 4 + a) * 68 + k];
#pragma unroll
            for (int b = 0; b < 4; ++b) bv[b] = *(float4*)&Bs[(tx * 4 + b) * 68 + k];
#pragma unroll
            for (int a = 0; a < 4; ++a)
#pragma unroll
                for (int b = 0; b < 4; ++b)
                    d[a][b] += av[a].x * bv[b].x + av[a].y * bv[b].y +
                               av[a].z * bv[b].z + av[a].w * bv[b].w;
        }
    }
    if (tid < 64) { redS[tid] = 0.f; redP[tid] = 0.f; }
    __syncthreads();
#pragma unroll
    for (int a = 0; a < 4; ++a) {
        int i = i0 + ty * 4 + a;
        float4 sm = *(const float4*)&sim[i * N + j0 + tx * 4];
        float s0 = expf(2.f * d[a][0]);
        float s1 = expf(2.f * d[a][1]);
        float s2 = expf(2.f * d[a][2]);
        float s3 = expf(2.f * d[a][3]);
        float rs = s0 + s1 + s2 + s3;
        float ps = (sm.x > 0.9f ? s0 : 0.f) + (sm.y > 0.9f ? s1 : 0.f) +
                   (sm.z > 0.9f ? s2 : 0.f) + (sm.w > 0.9f ? s3 : 0.f);
        atomicAdd(&redS[ty * 4 + a], rs);
        atomicAdd(&redP[ty * 4 + a], ps);
    }
    __syncthreads();
    if (tid < 64) {
        atomicAdd(&rowsum[i0 + tid], redS[tid]);
        atomicAdd(&pos4[i0 + tid], redP[tid]);
    }
}

// ------- clique/neighbor pos sums: one thread per (row, slot), deduped -------

__global__ __launch_bounds__(256) void k_pos_idx(const float* __restrict__ hn,
                                                 const int* __restrict__ cIdx,
                                                 const int* __restrict__ nIdx,
                                                 float* __restrict__ pos2,
                                                 float* __restrict__ pos3) {
    int g = blockIdx.x * blockDim.x + threadIdx.x;
    if (g >= N * 24) return;
    int i = g / 24, s = g % 24;
    const int* idx;
    int kk;
    float* dst;
    if (s < 8) { idx = cIdx + i * 8; kk = s; dst = pos2; }
    else       { idx = nIdx + i * 16; kk = s - 8; dst = pos3; }
    int t = idx[kk];
    for (int k = 0; k < kk; ++k)
        if (idx[k] == t) return;  // mask is a set: duplicates count once
    const float* a = hn + i * S0;
    const float* b = hn + t * S0;
    float d = 0.f;
    for (int k = 0; k < S0; ++k) d += a[k] * b[k];
    atomicAdd(dst + i, expf(2.f * d));
}

// ---------------- loss5: nonnegativity penalty ----------------

__global__ __launch_bounds__(256) void k_loss5(const float* __restrict__ U0,
                                               const float* __restrict__ U1,
                                               const float* __restrict__ U2,
                                               const float* __restrict__ V2,
                                               double* __restrict__ acc) {
    const int n0 = N * S0, n1 = S0 * S1, n2 = S1 * S2, n3 = S2 * N;
    const int total = n0 + n1 + n2 + n3;
    float local = 0.f;
    for (int t = blockIdx.x * blockDim.x + threadIdx.x; t < total;
         t += gridDim.x * blockDim.x) {
        int u = t;
        float x;
        if (u < n0) x = U0[u];
        else { u -= n0;
            if (u < n1) x = U1[u];
            else { u -= n1;
                if (u < n2) x = U2[u];
                else { u -= n2; x = V2[u]; }
            }
        }
        if (x < 0.f) local += x * x;
    }
    for (int off = 32; off; off >>= 1) local += __shfl_down(local, off, 64);
    if ((threadIdx.x & 63) == 0 && local != 0.f) atomicAdd(acc, (double)local);
}

// ---------------- finalize ----------------

__global__ __launch_bounds__(256) void k_final(const float* __restrict__ rowsum,
                                               const float* __restrict__ pos2,
                                               const float* __restrict__ pos3,
                                               const float* __restrict__ pos4,
                                               const double* __restrict__ lacc,
                                               float* __restrict__ out) {
    __shared__ double red[3][4];
    int tid = threadIdx.x;
    double l2 = 0, l3 = 0, l4 = 0;
    for (int i = tid; i < N; i += 256) {
        double rs = (double)rowsum[i];
        float p2 = pos2[i], p3 = pos3[i], p4 = pos4[i];
        if (p2 > 0.f) l2 -= log((double)p2 / rs);
        if (p3 > 0.f) l3 -= log((double)p3 / rs);
        if (p4 > 0.f) l4 -= log((double)p4 / rs);
    }
    int lane = tid & 63, wave = tid >> 6;
    for (int off = 32; off; off >>= 1) {
        l2 += __shfl_down(l2, off, 64);
        l3 += __shfl_down(l3, off, 64);
        l4 += __shfl_down(l4, off, 64);
    }
    if (lane == 0) { red[0][wave] = l2; red[1][wave] = l3; red[2][wave] = l4; }
    __syncthreads();
    if (tid == 0) {
        double L2 = 0, L3 = 0, L4 = 0;
        for (int w = 0; w < 4; ++w) { L2 += red[0][w]; L3 += red[1][w]; L4 += red[2][w]; }
        L2 /= N; L3 /= N; L4 /= N;
        double L1 = lacc[0], L5 = lacc[1];
        double total = L1 + 0.1 * (L2 + L3 + L4) + L5;
        out[0] = (float)total;
        out[1] = (float)L1;
        out[2] = (float)L2;
        out[3] = (float)L3;
        out[4] = (float)L4;
        out[5] = (float)L5;
    }
}

extern "C" void kernel_launch(void* const* d_in, const int* in_sizes, int n_in,
                              void* d_out, int out_size, void* d_ws, size_t ws_size,
                              hipStream_t stream) {
    const float* A     = (const float*)d_in[0];
    const float* U0    = (const float*)d_in[1];
    const float* U1    = (const float*)d_in[2];
    const float* U2    = (const float*)d_in[3];
    const float* V2    = (const float*)d_in[4];
    const float* fc1_w = (const float*)d_in[5];
    const float* fc1_b = (const float*)d_in[6];
    const float* fc2_w = (const float*)d_in[7];
    const float* fc2_b = (const float*)d_in[8];
    const float* sim   = (const float*)d_in[9];
    const int* cIdx    = (const int*)d_in[10];
    const int* nIdx    = (const int*)d_in[11];

    float* ws = (float*)d_ws;
    float* rowsum = ws;
    float* pos2 = ws + N;
    float* pos3 = ws + 2 * N;
    float* pos4 = ws + 3 * N;
    double* lacc = (double*)(ws + 4 * N);       // 2 doubles (loss1, loss5)
    float* T1 = ws + 4 * N + 4;                 // byte offset 65552, 16B-aligned
    float* W  = T1 + N * S1;
    float* H1 = W + N * S2;
    float* hn = H1 + N * S1;

    // zero accumulators (rowsum/pos arrays + doubles); ws is poisoned 0xAA
    hipMemsetAsync(ws, 0, (4 * N + 4) * sizeof(float), stream);

    k_t1<<<N / 8, 128, 0, stream>>>(U0, U1, T1);
    k_w<<<N / 8, 64, 0, stream>>>(T1, U2, W);
    k_h1<<<N / 8, 128, 0, stream>>>(V2, fc1_w, fc1_b, H1);
    k_hn<<<N / 8, 256, 0, stream>>>(H1, fc2_w, fc2_b, hn);
    k_loss1<<<dim3(N / 64, N / 64), 256, 0, stream>>>(W, V2, A, lacc);
    k_sim<<<dim3(N / 64, N / 64), 256, 0, stream>>>(hn, sim, rowsum, pos4);
    k_pos_idx<<<(N * 24) / 256, 256, 0, stream>>>(hn, cIdx, nIdx, pos2, pos3);
    k_loss5<<<1024, 256, 0, stream>>>(U0, U1, U2, V2, lacc + 1);
    k_final<<<1, 256, 0, stream>>>(rowsum, pos2, pos3, pos4, lacc, (float*)d_out);
}

// Round 2
// 320.373 us; speedup vs baseline: 1.6359x; 1.6359x over previous
//
#include <hip/hip_runtime.h>
#include <math.h>
#include <stdint.h>

#define N 4096
#define S0 256
#define S1 128
#define S2 64
#define LDK 72   // LDS row stride in bf16 (144 B): conflict-free for b128 frag reads

typedef __bf16 bf16;
typedef __attribute__((ext_vector_type(8))) __bf16 bf16x8;
typedef __attribute__((ext_vector_type(4))) float f32x4;

// ---------------- small chained GEMMs (fp32, minor cost) ----------------

// T1 = U0 @ U1 : (N,S0)@(S0,S1) -> (N,S1). 8 rows per block, 128 threads.
__global__ __launch_bounds__(128) void k_t1(const float* __restrict__ U0,
                                            const float* __restrict__ U1,
                                            float* __restrict__ T1) {
    __shared__ float u0s[8][S0];
    int i0 = blockIdx.x * 8;
    int tid = threadIdx.x;
    for (int t = tid; t < 8 * S0; t += 128)
        u0s[t / S0][t % S0] = U0[(i0 + t / S0) * S0 + (t % S0)];
    __syncthreads();
    int j = tid;
    float acc[8] = {0, 0, 0, 0, 0, 0, 0, 0};
    for (int k = 0; k < S0; ++k) {
        float u1 = U1[k * S1 + j];
#pragma unroll
        for (int r = 0; r < 8; ++r) acc[r] += u0s[r][k] * u1;
    }
    for (int r = 0; r < 8; ++r) T1[(i0 + r) * S1 + j] = acc[r];
}

// W = T1 @ U2 : (N,S1)@(S1,S2) -> (N,S2) in bf16. 8 rows per block, 64 threads.
__global__ __launch_bounds__(64) void k_w(const float* __restrict__ T1,
                                          const float* __restrict__ U2,
                                          bf16* __restrict__ Wb) {
    __shared__ float ts[8][S1];
    int i0 = blockIdx.x * 8;
    int tid = threadIdx.x;
    for (int t = tid; t < 8 * S1; t += 64)
        ts[t / S1][t % S1] = T1[(i0 + t / S1) * S1 + (t % S1)];
    __syncthreads();
    int j = tid;
    float acc[8] = {0, 0, 0, 0, 0, 0, 0, 0};
    for (int k = 0; k < S1; ++k) {
        float u2 = U2[k * S2 + j];
#pragma unroll
        for (int r = 0; r < 8; ++r) acc[r] += ts[r][k] * u2;
    }
    for (int r = 0; r < 8; ++r) Wb[(i0 + r) * S2 + j] = (bf16)acc[r];
}

// V2t = V2^T in bf16: (S2,N) -> (N,S2)
__global__ __launch_bounds__(256) void k_v2t(const float* __restrict__ V2,
                                             bf16* __restrict__ V2t) {
    __shared__ float t[64][65];
    int j0 = blockIdx.x * 64;
    for (int idx = threadIdx.x; idx < 4096; idx += 256) {
        int k = idx >> 6, c = idx & 63;
        t[c][k] = V2[k * N + j0 + c];
    }
    __syncthreads();
    for (int idx = threadIdx.x; idx < 4096; idx += 256) {
        int r = idx >> 6, k = idx & 63;
        V2t[(j0 + r) * 64 + k] = (bf16)t[r][k];
    }
}

// H1 = elu(V2^T @ fc1_w^T + fc1_b) : (N,S1). 8 rows per block, 128 threads.
__global__ __launch_bounds__(128) void k_h1(const float* __restrict__ V2,
                                            const float* __restrict__ fc1_w,
                                            const float* __restrict__ fc1_b,
                                            float* __restrict__ H1) {
    __shared__ float vs[8][S2];
    int i0 = blockIdx.x * 8;
    int tid = threadIdx.x;
    for (int t = tid; t < 8 * S2; t += 128) {
        int r = t % 8, k = t / 8;
        vs[r][k] = V2[k * N + i0 + r];
    }
    __syncthreads();
    int j = tid;
    float b = fc1_b[j];
    float acc[8];
#pragma unroll
    for (int r = 0; r < 8; ++r) acc[r] = b;
    for (int k = 0; k < S2; ++k) {
        float w = fc1_w[j * S2 + k];
#pragma unroll
        for (int r = 0; r < 8; ++r) acc[r] += vs[r][k] * w;
    }
    for (int r = 0; r < 8; ++r) {
        float x = acc[r];
        H1[(i0 + r) * S1 + j] = x > 0.f ? x : (expf(x) - 1.f);
    }
}

// H = H1 @ fc2_w^T + fc2_b, L2-normalize rows -> hnb (N,S0) bf16.
__global__ __launch_bounds__(256) void k_hn(const float* __restrict__ H1,
                                            const float* __restrict__ fc2_w,
                                            const float* __restrict__ fc2_b,
                                            bf16* __restrict__ hnb) {
    __shared__ float hs[8][S1];
    __shared__ float red[4][8];
    __shared__ float norms[8];
    int i0 = blockIdx.x * 8;
    int tid = threadIdx.x;
    for (int t = tid; t < 8 * S1; t += 256)
        hs[t / S1][t % S1] = H1[(i0 + t / S1) * S1 + (t % S1)];
    __syncthreads();
    int j = tid;
    float b = fc2_b[j];
    float acc[8];
#pragma unroll
    for (int r = 0; r < 8; ++r) acc[r] = b;
    for (int k = 0; k < S1; ++k) {
        float w = fc2_w[j * S1 + k];
#pragma unroll
        for (int r = 0; r < 8; ++r) acc[r] += hs[r][k] * w;
    }
    int lane = tid & 63, wave = tid >> 6;
#pragma unroll
    for (int r = 0; r < 8; ++r) {
        float v = acc[r] * acc[r];
        for (int off = 32; off; off >>= 1) v += __shfl_down(v, off, 64);
        if (lane == 0) red[wave][r] = v;
    }
    __syncthreads();
    if (tid < 8) {
        float s = red[0][tid] + red[1][tid] + red[2][tid] + red[3][tid];
        norms[tid] = fmaxf(sqrtf(s), 1e-12f);
    }
    __syncthreads();
    for (int r = 0; r < 8; ++r)
        hnb[(i0 + r) * S0 + j] = (bf16)(acc[r] / norms[r]);
}

// ------- loss1: sum((A - Wb@V2t^T)^2), 128x128 MFMA tiles, K=64 -------

__global__ __launch_bounds__(256) void k_loss1(const bf16* __restrict__ Wb,
                                               const bf16* __restrict__ V2t,
                                               const float* __restrict__ A,
                                               double* __restrict__ acc) {
    __shared__ bf16 As[128 * LDK];
    __shared__ bf16 Bs[128 * LDK];
    __shared__ double redd[4];
    int tid = threadIdx.x;
    int lane = tid & 63, w = tid >> 6;
    int i0 = blockIdx.y * 128, j0 = blockIdx.x * 128;
    int wm = (w >> 1) * 64, wn = (w & 1) * 64;

    f32x4 zero = {0.f, 0.f, 0.f, 0.f};
    f32x4 d[4][4];
#pragma unroll
    for (int a = 0; a < 4; ++a)
#pragma unroll
        for (int b = 0; b < 4; ++b) d[a][b] = zero;

#pragma unroll
    for (int t = 0; t < 4; ++t) {
        int idx = tid + 256 * t;
        int r = idx >> 3, c = idx & 7;
        uint4 va = *(const uint4*)(Wb + (i0 + r) * S2 + c * 8);
        uint4 vb = *(const uint4*)(V2t + (j0 + r) * S2 + c * 8);
        *(uint4*)(As + r * LDK + c * 8) = va;
        *(uint4*)(Bs + r * LDK + c * 8) = vb;
    }
    __syncthreads();
    int q = lane >> 4, l15 = lane & 15;
#pragma unroll
    for (int kk = 0; kk < 64; kk += 32) {
        bf16x8 af[4], bfr[4];
#pragma unroll
        for (int ta = 0; ta < 4; ++ta)
            af[ta] = *(const bf16x8*)(As + (wm + ta * 16 + l15) * LDK + kk + q * 8);
#pragma unroll
        for (int tb = 0; tb < 4; ++tb)
            bfr[tb] = *(const bf16x8*)(Bs + (wn + tb * 16 + l15) * LDK + kk + q * 8);
#pragma unroll
        for (int ta = 0; ta < 4; ++ta)
#pragma unroll
            for (int tb = 0; tb < 4; ++tb)
                d[ta][tb] = __builtin_amdgcn_mfma_f32_16x16x32_bf16(af[ta], bfr[tb], d[ta][tb], 0, 0, 0);
    }
    float local = 0.f;
#pragma unroll
    for (int ta = 0; ta < 4; ++ta)
#pragma unroll
        for (int v = 0; v < 4; ++v) {
            int i = i0 + wm + ta * 16 + q * 4 + v;
#pragma unroll
            for (int tb = 0; tb < 4; ++tb) {
                int j = j0 + wn + tb * 16 + l15;
                float e = A[i * N + j] - d[ta][tb][v];
                local += e * e;
            }
        }
    double dl = (double)local;
    for (int off = 32; off; off >>= 1) dl += __shfl_down(dl, off, 64);
    if (lane == 0) redd[w] = dl;
    __syncthreads();
    if (tid == 0) atomicAdd(acc, redd[0] + redd[1] + redd[2] + redd[3]);
}

// ------- fused refl_sim: rowsum + sim-mask pos, 128x128 MFMA tiles, K=256 -------

__global__ __launch_bounds__(256) void k_sim(const bf16* __restrict__ hnb,
                                             const float* __restrict__ sim,
                                             float* __restrict__ rowsum,
                                             float* __restrict__ pos4) {
    __shared__ bf16 As[128 * LDK];
    __shared__ bf16 Bs[128 * LDK];
    __shared__ float rs_l[128], ps_l[128];
    int tid = threadIdx.x;
    int lane = tid & 63, w = tid >> 6;
    int i0 = blockIdx.y * 128, j0 = blockIdx.x * 128;
    int wm = (w >> 1) * 64, wn = (w & 1) * 64;
    if (tid < 128) { rs_l[tid] = 0.f; ps_l[tid] = 0.f; }

    f32x4 zero = {0.f, 0.f, 0.f, 0.f};
    f32x4 d[4][4];
#pragma unroll
    for (int a = 0; a < 4; ++a)
#pragma unroll
        for (int b = 0; b < 4; ++b) d[a][b] = zero;

    int q = lane >> 4, l15 = lane & 15;
    for (int k0 = 0; k0 < S0; k0 += 64) {
        __syncthreads();
#pragma unroll
        for (int t = 0; t < 4; ++t) {
            int idx = tid + 256 * t;
            int r = idx >> 3, c = idx & 7;
            uint4 va = *(const uint4*)(hnb + (i0 + r) * S0 + k0 + c * 8);
            uint4 vb = *(const uint4*)(hnb + (j0 + r) * S0 + k0 + c * 8);
            *(uint4*)(As + r * LDK + c * 8) = va;
            *(uint4*)(Bs + r * LDK + c * 8) = vb;
        }
        __syncthreads();
#pragma unroll
        for (int kk = 0; kk < 64; kk += 32) {
            bf16x8 af[4], bfr[4];
#pragma unroll
            for (int ta = 0; ta < 4; ++ta)
                af[ta] = *(const bf16x8*)(As + (wm + ta * 16 + l15) * LDK + kk + q * 8);
#pragma unroll
            for (int tb = 0; tb < 4; ++tb)
                bfr[tb] = *(const bf16x8*)(Bs + (wn + tb * 16 + l15) * LDK + kk + q * 8);
#pragma unroll
            for (int ta = 0; ta < 4; ++ta)
#pragma unroll
                for (int tb = 0; tb < 4; ++tb)
                    d[ta][tb] = __builtin_amdgcn_mfma_f32_16x16x32_bf16(af[ta], bfr[tb], d[ta][tb], 0, 0, 0);
        }
    }
    // epilogue: s = exp(2*dot); rowsum += s; pos4 += masked s
#pragma unroll
    for (int ta = 0; ta < 4; ++ta)
#pragma unroll
        for (int v = 0; v < 4; ++v) {
            int li = wm + ta * 16 + q * 4 + v;
            int i = i0 + li;
            float rs = 0.f, ps = 0.f;
#pragma unroll
            for (int tb = 0; tb < 4; ++tb) {
                int j = j0 + wn + tb * 16 + l15;
                float s = __expf(2.f * d[ta][tb][v]);
                rs += s;
                ps += (sim[i * N + j] > 0.9f) ? s : 0.f;
            }
#pragma unroll
            for (int m = 1; m < 16; m <<= 1) {
                rs += __shfl_xor(rs, m, 16);
                ps += __shfl_xor(ps, m, 16);
            }
            if (l15 == 0) {
                atomicAdd(&rs_l[li], rs);
                atomicAdd(&ps_l[li], ps);
            }
        }
    __syncthreads();
    if (tid < 128) {
        atomicAdd(&rowsum[i0 + tid], rs_l[tid]);
        atomicAdd(&pos4[i0 + tid], ps_l[tid]);
    }
}

// ------- clique/neighbor pos sums: one thread per (row, slot), deduped -------

__global__ __launch_bounds__(256) void k_pos_idx(const bf16* __restrict__ hnb,
                                                 const int* __restrict__ cIdx,
                                                 const int* __restrict__ nIdx,
                                                 float* __restrict__ pos2,
                                                 float* __restrict__ pos3) {
    int g = blockIdx.x * blockDim.x + threadIdx.x;
    if (g >= N * 24) return;
    int i = g / 24, s = g % 24;
    const int* idx;
    int kk;
    float* dst;
    if (s < 8) { idx = cIdx + i * 8; kk = s; dst = pos2; }
    else       { idx = nIdx + i * 16; kk = s - 8; dst = pos3; }
    int t = idx[kk];
    for (int k = 0; k < kk; ++k)
        if (idx[k] == t) return;  // mask is a set: duplicates count once
    const bf16* a = hnb + i * S0;
    const bf16* b = hnb + t * S0;
    float dsum = 0.f;
    for (int k = 0; k < S0; k += 8) {
        bf16x8 av = *(const bf16x8*)(a + k);
        bf16x8 bv = *(const bf16x8*)(b + k);
#pragma unroll
        for (int u = 0; u < 8; ++u) dsum += (float)av[u] * (float)bv[u];
    }
    atomicAdd(dst + i, __expf(2.f * dsum));
}

// ---------------- loss5: nonnegativity penalty ----------------

__global__ __launch_bounds__(256) void k_loss5(const float* __restrict__ U0,
                                               const float* __restrict__ U1,
                                               const float* __restrict__ U2,
                                               const float* __restrict__ V2,
                                               double* __restrict__ acc) {
    const int n0 = N * S0, n1 = S0 * S1, n2 = S1 * S2, n3 = S2 * N;
    const int total = n0 + n1 + n2 + n3;
    float local = 0.f;
    for (int t = blockIdx.x * blockDim.x + threadIdx.x; t < total;
         t += gridDim.x * blockDim.x) {
        int u = t;
        float x;
        if (u < n0) x = U0[u];
        else { u -= n0;
            if (u < n1) x = U1[u];
            else { u -= n1;
                if (u < n2) x = U2[u];
                else { u -= n2; x = V2[u]; }
            }
        }
        if (x < 0.f) local += x * x;
    }
    for (int off = 32; off; off >>= 1) local += __shfl_down(local, off, 64);
    if ((threadIdx.x & 63) == 0 && local != 0.f) atomicAdd(acc, (double)local);
}

// ---------------- finalize ----------------

__global__ __launch_bounds__(256) void k_final(const float* __restrict__ rowsum,
                                               const float* __restrict__ pos2,
                                               const float* __restrict__ pos3,
                                               const float* __restrict__ pos4,
                                               const double* __restrict__ lacc,
                                               float* __restrict__ out) {
    __shared__ double red[3][4];
    int tid = threadIdx.x;
    double l2 = 0, l3 = 0, l4 = 0;
    for (int i = tid; i < N; i += 256) {
        double rs = (double)rowsum[i];
        float p2 = pos2[i], p3 = pos3[i], p4 = pos4[i];
        if (p2 > 0.f) l2 -= log((double)p2 / rs);
        if (p3 > 0.f) l3 -= log((double)p3 / rs);
        if (p4 > 0.f) l4 -= log((double)p4 / rs);
    }
    int lane = tid & 63, wave = tid >> 6;
    for (int off = 32; off; off >>= 1) {
        l2 += __shfl_down(l2, off, 64);
        l3 += __shfl_down(l3, off, 64);
        l4 += __shfl_down(l4, off, 64);
    }
    if (lane == 0) { red[0][wave] = l2; red[1][wave] = l3; red[2][wave] = l4; }
    __syncthreads();
    if (tid == 0) {
        double L2 = 0, L3 = 0, L4 = 0;
        for (int w = 0; w < 4; ++w) { L2 += red[0][w]; L3 += red[1][w]; L4 += red[2][w]; }
        L2 /= N; L3 /= N; L4 /= N;
        double L1 = lacc[0], L5 = lacc[1];
        double total = L1 + 0.1 * (L2 + L3 + L4) + L5;
        out[0] = (float)total;
        out[1] = (float)L1;
        out[2] = (float)L2;
        out[3] = (float)L3;
        out[4] = (float)L4;
        out[5] = (float)L5;
    }
}

extern "C" void kernel_launch(void* const* d_in, const int* in_sizes, int n_in,
                              void* d_out, int out_size, void* d_ws, size_t ws_size,
                              hipStream_t stream) {
    const float* A     = (const float*)d_in[0];
    const float* U0    = (const float*)d_in[1];
    const float* U1    = (const float*)d_in[2];
    const float* U2    = (const float*)d_in[3];
    const float* V2    = (const float*)d_in[4];
    const float* fc1_w = (const float*)d_in[5];
    const float* fc1_b = (const float*)d_in[6];
    const float* fc2_w = (const float*)d_in[7];
    const float* fc2_b = (const float*)d_in[8];
    const float* sim   = (const float*)d_in[9];
    const int* cIdx    = (const int*)d_in[10];
    const int* nIdx    = (const int*)d_in[11];

    float* ws = (float*)d_ws;
    float* rowsum = ws;
    float* pos2 = ws + N;
    float* pos3 = ws + 2 * N;
    float* pos4 = ws + 3 * N;
    double* lacc = (double*)(ws + 4 * N);          // 2 doubles (loss1, loss5)
    float* T1 = ws + 4 * N + 4;                    // N*S1 fp32
    float* H1 = T1 + N * S1;                       // N*S1 fp32
    bf16* hnb = (bf16*)(H1 + N * S1);              // N*S0 bf16 (16B-aligned)
    bf16* Wb  = hnb + N * S0;                      // N*S2 bf16
    bf16* V2t = Wb + N * S2;                       // N*S2 bf16

    hipMemsetAsync(ws, 0, (4 * N + 4) * sizeof(float), stream);

    k_t1<<<N / 8, 128, 0, stream>>>(U0, U1, T1);
    k_w<<<N / 8, 64, 0, stream>>>(T1, U2, Wb);
    k_v2t<<<N / 64, 256, 0, stream>>>(V2, V2t);
    k_h1<<<N / 8, 128, 0, stream>>>(V2, fc1_w, fc1_b, H1);
    k_hn<<<N / 8, 256, 0, stream>>>(H1, fc2_w, fc2_b, hnb);
    k_loss1<<<dim3(N / 128, N / 128), 256, 0, stream>>>(Wb, V2t, A, lacc);
    k_sim<<<dim3(N / 128, N / 128), 256, 0, stream>>>(hnb, sim, rowsum, pos4);
    k_pos_idx<<<(N * 24) / 256, 256, 0, stream>>>(hnb, cIdx, nIdx, pos2, pos3);
    k_loss5<<<1024, 256, 0, stream>>>(U0, U1, U2, V2, lacc + 1);
    k_final<<<1, 256, 0, stream>>>(rowsum, pos2, pos3, pos4, lacc, (float*)d_out);
}